// Round 13
// baseline (414.577 us; speedup 1.0000x reference)
//
#include <hip/hip_runtime.h>
#include <stdint.h>

#define S_LEN 2048
#define BATCH 2
#define HIDDEN 2560
#define NH 8
#define NKV 4
#define HD 256
#define QSZ (NH*HD)          // 2048
#define NQKV 4096            // QSZ + 2*KVSZ
#define MROWS (BATCH*S_LEN)  // 4096
#define SCALE_ATT 0.0625f

using bf16x8 = __attribute__((__ext_vector_type__(8))) __bf16;
using f32x4  = __attribute__((__ext_vector_type__(4))) float;
using s16x8  = __attribute__((__ext_vector_type__(8))) short;

union B8u { s16x8 s; bf16x8 b; };
union I4B8 { int4 i; bf16x8 b; };

__device__ __forceinline__ unsigned short f2bf(float x){
  unsigned u = __float_as_uint(x);
  u += 0x7fffu + ((u >> 16) & 1u);
  return (unsigned short)(u >> 16);
}
__device__ __forceinline__ bf16x8 ld_bf8(const unsigned short* p){
  B8u u; u.s = *reinterpret_cast<const s16x8*>(p); return u.b;
}
__device__ __forceinline__ f32x4 mfma16(bf16x8 a, bf16x8 b, f32x4 c){
  return __builtin_amdgcn_mfma_f32_16x16x32_bf16(a, b, c, 0, 0, 0);
}
__device__ __forceinline__ void gload16(const void* g, void* l){
  __builtin_amdgcn_global_load_lds((const __attribute__((address_space(1))) void*)g,
                                   (__attribute__((address_space(3))) void*)l,
                                   16, 0, 0);
}
__device__ __forceinline__ int cvtpk(float lo, float hi){
  int r;
  asm("v_cvt_pk_bf16_f32 %0, %1, %2" : "=v"(r) : "v"(lo), "v"(hi));
  return r;
}

// ---------------- cast fp32 -> bf16 (flat) ----------------
__global__ __launch_bounds__(256) void cast_bf16_kernel(
    const float* __restrict__ in, unsigned short* __restrict__ out, int n)
{
  int i = (blockIdx.x * 256 + threadIdx.x) * 4;
  if (i < n){
    float4 v = *reinterpret_cast<const float4*>(in + i);
    ushort4 o;
    o.x = f2bf(v.x); o.y = f2bf(v.y); o.z = f2bf(v.z); o.w = f2bf(v.w);
    *reinterpret_cast<ushort4*>(out + i) = o;
  }
}

// ---------------- transpose + cast: in[R][C] fp32 -> out[C][R] bf16 ----------------
__global__ __launch_bounds__(256) void tcast_kernel(
    const float* __restrict__ in, unsigned short* __restrict__ out, int R, int C)
{
  __shared__ float t[32][33];
  int c0 = blockIdx.x * 32, r0 = blockIdx.y * 32;
  int tx = threadIdx.x & 31, ty = threadIdx.x >> 5;
#pragma unroll
  for (int ii = 0; ii < 4; ii++)
    t[ty + ii*8][tx] = in[(size_t)(r0 + ty + ii*8) * C + c0 + tx];
  __syncthreads();
#pragma unroll
  for (int ii = 0; ii < 4; ii++)
    out[(size_t)(c0 + ty + ii*8) * R + r0 + tx] = f2bf(t[tx][ty + ii*8]);
}

// ---------------- RoPE cos/sin tables: [b][c(128)][s(2048)] f32 ----------------
__global__ __launch_bounds__(256) void ropetab_kernel(
    const int* __restrict__ positions, float* __restrict__ ct, float* __restrict__ st)
{
  const int cix = blockIdx.x;
  const int b   = blockIdx.y;
  const float kln = -9.210340371976184f / 128.0f;   // -ln(10000)/128
  const float inv = expf((float)cix * kln);
  float* cp = ct + ((size_t)b * 128 + cix) * 2048;
  float* sp = st + ((size_t)b * 128 + cix) * 2048;
  for (int s = threadIdx.x; s < S_LEN; s += 256){
    float fpos = (float)positions[b * S_LEN + s];
    float sv, cv;
    sincosf(fpos * inv, &sv, &cv);
    cp[s] = cv;
    sp[s] = sv;
  }
}

// ================= GEMM1 fused: 256x256 8-wave pipelined + RMSNorm/RoPE epilogue =====
__global__ __launch_bounds__(512, 2) void gemm_qkv_kernel(
    const unsigned short* __restrict__ A,
    const unsigned short* __restrict__ BT,
    const float* __restrict__ qw, const float* __restrict__ kw,
    const float* __restrict__ ct, const float* __restrict__ st,
    unsigned short* __restrict__ qB,
    unsigned short* __restrict__ kB,
    unsigned short* __restrict__ vT)
{
  __shared__ unsigned short Ab[2][256 * 64];
  __shared__ unsigned short Bb[2][256 * 64];

  const int K = HIDDEN;
  const int nbn = 16;
  const int tid  = threadIdx.x;
  const int lane = tid & 63;
  const int wid  = tid >> 6;
  const int wm = wid >> 2, wn = wid & 3;
  const int lq = lane & 15, lk = lane >> 4;

  const int cpx = gridDim.x >> 3;
  const int wg  = (blockIdx.x & 7) * cpx + (blockIdx.x >> 3);
  const int bm = wg / nbn, bn = wg % nbn;

  const int l8 = lane >> 3;
  const int sl = ((lane & 7) ^ l8) * 8;
  const unsigned short* agS = A  + (size_t)(bm*256 + wid*16 + l8) * K + sl;
  const unsigned short* bgS = BT + (size_t)(bn*256 + wid*16 + l8) * K + sl;

  f32x4 acc[4][4][2] = {};
  bf16x8 a[4][2], b[2][2];

#define STA(c, h, tt) do {                                                    \
    unsigned short* d = &Ab[c][(h)*8192 + wid*1024];                          \
    const unsigned short* s = agS + (size_t)(h)*128*K + (size_t)(tt)*64;      \
    gload16(s, d); gload16(s + 8*(size_t)K, d + 512);                         \
  } while (0)
#define STB(c, h, tt) do {                                                    \
    unsigned short* d = &Bb[c][(h)*8192 + wid*1024];                          \
    const unsigned short* s = bgS + (size_t)(h)*128*K + (size_t)(tt)*64;      \
    gload16(s, d); gload16(s + 8*(size_t)K, d + 512);                         \
  } while (0)
#define LDA(qa) do {                                                          \
    _Pragma("unroll") for (int m = 0; m < 4; m++)                             \
    _Pragma("unroll") for (int kk = 0; kk < 2; kk++)                          \
      a[m][kk] = ld_bf8(&Ab[cur][((qa)*128 + wm*64 + m*16 + lq)*64            \
                                 + (((kk*4 + lk) ^ (lq & 7)) << 3)]);         \
  } while (0)
#define LDB(qb) do {                                                          \
    _Pragma("unroll") for (int n = 0; n < 2; n++)                             \
    _Pragma("unroll") for (int kk = 0; kk < 2; kk++)                          \
      b[n][kk] = ld_bf8(&Bb[cur][((qb)*128 + wn*32 + n*16 + lq)*64            \
                                 + (((kk*4 + lk) ^ (lq & 7)) << 3)]);         \
  } while (0)
#define MM(qi) do {                                                           \
    __builtin_amdgcn_s_setprio(1);                                            \
    _Pragma("unroll") for (int m = 0; m < 4; m++)                             \
    _Pragma("unroll") for (int n = 0; n < 2; n++)                             \
    _Pragma("unroll") for (int kk = 0; kk < 2; kk++)                          \
      acc[qi][m][n] = mfma16(a[m][kk], b[n][kk], acc[qi][m][n]);              \
    __builtin_amdgcn_s_setprio(0);                                            \
  } while (0)
#define BARR __builtin_amdgcn_s_barrier()
#define VM(n) asm volatile("s_waitcnt vmcnt(" #n ")" ::: "memory")

  STA(0, 0, 0); STB(0, 0, 0); STB(0, 1, 0); STA(0, 1, 0);
  VM(4); BARR;

  const int NT = K >> 6;
  for (int t = 0; t < NT - 1; ++t){
    const int cur = t & 1, nxt = cur ^ 1;
    LDA(0); LDB(0); STA(nxt, 0, t+1);
    BARR; MM(0); VM(4); BARR;
    LDB(1);         STB(nxt, 0, t+1);
    BARR; MM(1); VM(4); BARR;
    LDA(1);         STB(nxt, 1, t+1);
    BARR; MM(2);        BARR;
    LDB(0);         STA(nxt, 1, t+1);
    BARR; MM(3); VM(4); BARR;
  }
  {
    const int cur = (NT - 1) & 1;
    LDA(0); LDB(0); BARR; MM(0); VM(2); BARR;
    LDB(1);         BARR; MM(1); VM(0); BARR;
    LDA(1);         BARR; MM(2);        BARR;
    LDB(0);         BARR; MM(3);        BARR;
  }
#undef STA
#undef STB
#undef LDA
#undef LDB
#undef MM
#undef BARR
#undef VM

  // ---------- fused epilogue ----------
  __syncthreads();
  const int b_  = bm >> 3;
  const int sb0 = (bm & 7) * 256;

  if (bn >= 12){
    const int mhv = bn - 12;
#pragma unroll
    for (int qi = 0; qi < 4; qi++){
      const int qa = qi >> 1, qb = (qi ^ (qi >> 1)) & 1;
#pragma unroll
      for (int m = 0; m < 4; m++){
        const int s0 = sb0 + qa*128 + wm*64 + m*16 + lk*4;
#pragma unroll
        for (int n = 0; n < 2; n++){
          const int d = qb*128 + wn*32 + n*16 + lq;
          ushort4 o;
          o.x = f2bf(acc[qi][m][n][0]);
          o.y = f2bf(acc[qi][m][n][1]);
          o.z = f2bf(acc[qi][m][n][2]);
          o.w = f2bf(acc[qi][m][n][3]);
          *reinterpret_cast<ushort4*>(
              vT + ((size_t)((b_*NKV + mhv)*HD + d))*S_LEN + s0) = o;
        }
      }
    }
  } else {
    float* red = (float*)Ab;
    float part[2][4][4];
#pragma unroll
    for (int qa = 0; qa < 2; qa++){
      const int qiA = qa ? 3 : 0, qiB = qa ? 2 : 1;
#pragma unroll
      for (int m = 0; m < 4; m++)
#pragma unroll
      for (int i = 0; i < 4; i++){
        float s = 0.f;
#pragma unroll
        for (int n = 0; n < 2; n++)
          s += acc[qiA][m][n][i]*acc[qiA][m][n][i]
             + acc[qiB][m][n][i]*acc[qiB][m][n][i];
        s += __shfl_xor(s, 1, 64);
        s += __shfl_xor(s, 2, 64);
        s += __shfl_xor(s, 4, 64);
        s += __shfl_xor(s, 8, 64);
        part[qa][m][i] = s;
      }
    }
    if (lq == 0){
#pragma unroll
      for (int qa = 0; qa < 2; qa++)
#pragma unroll
      for (int m = 0; m < 4; m++)
#pragma unroll
      for (int i = 0; i < 4; i++)
        red[wn*256 + qa*128 + wm*64 + m*16 + lk*4 + i] = part[qa][m][i];
    }
    __syncthreads();
    float rsv[2][4][4];
#pragma unroll
    for (int qa = 0; qa < 2; qa++)
#pragma unroll
    for (int m = 0; m < 4; m++)
#pragma unroll
    for (int i = 0; i < 4; i++){
      const int row = qa*128 + wm*64 + m*16 + lk*4 + i;
      float tt = red[row] + red[256 + row] + red[512 + row] + red[768 + row];
      rsv[qa][m][i] = rsqrtf(tt * (1.0f/256.0f) + 1e-6f);
    }
    const float* wv = (bn < 8) ? qw : kw;
    unsigned short* dstB = (bn < 8)
      ? qB + ((size_t)(b_*NH  + bn      ) * S_LEN) * HD
      : kB + ((size_t)(b_*NKV + (bn - 8)) * S_LEN) * HD;
    const float* ctb = ct + (size_t)b_ * 128 * 2048;
    const float* stb = st + (size_t)b_ * 128 * 2048;
#pragma unroll
    for (int qa = 0; qa < 2; qa++){
      const int qiA = qa ? 3 : 0, qiB = qa ? 2 : 1;
#pragma unroll
      for (int m = 0; m < 4; m++){
        const int s0 = sb0 + qa*128 + wm*64 + m*16 + lk*4;
#pragma unroll
        for (int n = 0; n < 2; n++){
          const int c0 = wn*32 + n*16 + lq;
          const float w0 = 1.0f + wv[c0];
          const float w1 = 1.0f + wv[c0 + 128];
          const float4 c4 = *reinterpret_cast<const float4*>(ctb + (size_t)c0*2048 + s0);
          const float4 s4 = *reinterpret_cast<const float4*>(stb + (size_t)c0*2048 + s0);
#pragma unroll
          for (int i = 0; i < 4; i++){
            const float rs_ = rsv[qa][m][i];
            const float y0 = acc[qiA][m][n][i] * rs_ * w0;
            const float y1 = acc[qiB][m][n][i] * rs_ * w1;
            const float cc = (&c4.x)[i], ss = (&s4.x)[i];
            unsigned short* p = dstB + (size_t)(s0 + i) * HD;
            p[c0]       = f2bf(y0 * cc - y1 * ss);
            p[c0 + 128] = f2bf(y1 * cc + y0 * ss);
          }
        }
      }
    }
  }
}

// ================= 256x256 8-wave deep-pipelined GEMM (f32 out, for GEMM2) ==========
__global__ __launch_bounds__(512, 2) void gemm256_kernel(
    const unsigned short* __restrict__ A,
    const unsigned short* __restrict__ BT,
    float* __restrict__ C,
    int N, int K, int nbn)
{
  __shared__ unsigned short Ab[2][256 * 64];
  __shared__ unsigned short Bb[2][256 * 64];

  const int tid  = threadIdx.x;
  const int lane = tid & 63;
  const int wid  = tid >> 6;
  const int wm = wid >> 2, wn = wid & 3;
  const int lq = lane & 15, lk = lane >> 4;

  const int cpx = gridDim.x >> 3;
  const int wg  = (blockIdx.x & 7) * cpx + (blockIdx.x >> 3);
  const int bm = wg / nbn, bn = wg % nbn;

  const int l8 = lane >> 3;
  const int sl = ((lane & 7) ^ l8) * 8;
  const unsigned short* agS = A  + (size_t)(bm*256 + wid*16 + l8) * K + sl;
  const unsigned short* bgS = BT + (size_t)(bn*256 + wid*16 + l8) * K + sl;

  f32x4 acc[4][4][2] = {};
  bf16x8 a[4][2], b[2][2];

#define STA(c, h, tt) do {                                                    \
    unsigned short* d = &Ab[c][(h)*8192 + wid*1024];                          \
    const unsigned short* s = agS + (size_t)(h)*128*K + (size_t)(tt)*64;      \
    gload16(s, d); gload16(s + 8*(size_t)K, d + 512);                         \
  } while (0)
#define STB(c, h, tt) do {                                                    \
    unsigned short* d = &Bb[c][(h)*8192 + wid*1024];                          \
    const unsigned short* s = bgS + (size_t)(h)*128*K + (size_t)(tt)*64;      \
    gload16(s, d); gload16(s + 8*(size_t)K, d + 512);                         \
  } while (0)
#define LDA(qa) do {                                                          \
    _Pragma("unroll") for (int m = 0; m < 4; m++)                             \
    _Pragma("unroll") for (int kk = 0; kk < 2; kk++)                          \
      a[m][kk] = ld_bf8(&Ab[cur][((qa)*128 + wm*64 + m*16 + lq)*64            \
                                 + (((kk*4 + lk) ^ (lq & 7)) << 3)]);         \
  } while (0)
#define LDB(qb) do {                                                          \
    _Pragma("unroll") for (int n = 0; n < 2; n++)                             \
    _Pragma("unroll") for (int kk = 0; kk < 2; kk++)                          \
      b[n][kk] = ld_bf8(&Bb[cur][((qb)*128 + wn*32 + n*16 + lq)*64            \
                                 + (((kk*4 + lk) ^ (lq & 7)) << 3)]);         \
  } while (0)
#define MM(qi) do {                                                           \
    __builtin_amdgcn_s_setprio(1);                                            \
    _Pragma("unroll") for (int m = 0; m < 4; m++)                             \
    _Pragma("unroll") for (int n = 0; n < 2; n++)                             \
    _Pragma("unroll") for (int kk = 0; kk < 2; kk++)                          \
      acc[qi][m][n] = mfma16(a[m][kk], b[n][kk], acc[qi][m][n]);              \
    __builtin_amdgcn_s_setprio(0);                                            \
  } while (0)
#define BARR __builtin_amdgcn_s_barrier()
#define VM(n) asm volatile("s_waitcnt vmcnt(" #n ")" ::: "memory")

  STA(0, 0, 0); STB(0, 0, 0); STB(0, 1, 0); STA(0, 1, 0);
  VM(4); BARR;

  const int NT = K >> 6;
  for (int t = 0; t < NT - 1; ++t){
    const int cur = t & 1, nxt = cur ^ 1;
    LDA(0); LDB(0); STA(nxt, 0, t+1);
    BARR; MM(0); VM(4); BARR;
    LDB(1);         STB(nxt, 0, t+1);
    BARR; MM(1); VM(4); BARR;
    LDA(1);         STB(nxt, 1, t+1);
    BARR; MM(2);        BARR;
    LDB(0);         STA(nxt, 1, t+1);
    BARR; MM(3); VM(4); BARR;
  }
  {
    const int cur = (NT - 1) & 1;
    LDA(0); LDB(0); BARR; MM(0); VM(2); BARR;
    LDB(1);         BARR; MM(1); VM(0); BARR;
    LDA(1);         BARR; MM(2);        BARR;
    LDB(0);         BARR; MM(3);        BARR;
  }
#undef STA
#undef STB
#undef LDA
#undef LDB
#undef MM
#undef BARR
#undef VM

#pragma unroll
  for (int qi = 0; qi < 4; qi++){
    const int qa = qi >> 1;
    const int qb = (qi ^ (qi >> 1)) & 1;
    const int r0 = bm*256 + qa*128 + wm*64;
    const int c0 = bn*256 + qb*128 + wn*32;
#pragma unroll
    for (int m = 0; m < 4; m++)
#pragma unroll
      for (int n = 0; n < 2; n++)
#pragma unroll
        for (int i = 0; i < 4; i++)
          C[(size_t)(r0 + m*16 + lk*4 + i) * N + (c0 + n*16 + lq)] = acc[qi][m][n][i];
  }
}

// ---------------- mask bit pack + work-queue counter reset ----------------
__global__ void maskbits_kernel(const int* __restrict__ amask, unsigned* __restrict__ bm,
                                int* __restrict__ ctr)
{
  int t = threadIdx.x;                 // 0..127
  int b = t >> 6, tile = t & 63;
  unsigned m = 0;
  for (int j = 0; j < 32; j++)
    m |= (amask[b * S_LEN + tile * 32 + j] != 0 ? 1u : 0u) << j;
  bm[t] = m;
  if (t < 8) ctr[t] = 0;
}

// ---------------- flash attention v12: 32 q-rows/wave (2 row-sets), K/V reads amortized --
// Grid 256 (1 block/CU). combo c = blockIdx.x&7 -> (mh,b); per-combo queue of 32 items
// of 64 q-rows, heavy-first. Block = 4 waves = 2 heads x 2 q-subtiles(32 rows each).
// Each wave reads a K/V fragment ONCE and feeds TWO row-sets of MFMAs -> LDS-read
// traffic per q-row halves (the R12-diagnosed bottleneck). R8 2-deep pipeline.
__global__ __launch_bounds__(256) void attn_kernel(
    const unsigned short* __restrict__ qB,
    const unsigned short* __restrict__ kB,
    const unsigned short* __restrict__ vT,
    const unsigned* __restrict__ bmG,
    unsigned short* __restrict__ attnO,
    int* __restrict__ ctr)
{
  __shared__ unsigned short Kb[2][32 * 256];
  __shared__ unsigned short Vb[2][256 * 32];
  __shared__ unsigned bm_lds[64];
  __shared__ int s_idx;

  const int tid  = threadIdx.x;
  const int lane = tid & 63, wid = tid >> 6;
  const int c  = blockIdx.x & 7;
  const int mh = c & 3, b = c >> 2;
  const int h  = mh * 2 + (wid >> 1);
  const int lq = lane & 15, lk = lane >> 4;

  if (tid < 64) bm_lds[tid] = bmG[(b << 6) + tid];

  const unsigned short* kbase = kB + (size_t)(b * NKV + mh) * S_LEN * HD;
  const unsigned short* vbase = vT + (size_t)(b * NKV + mh) * HD * S_LEN;
  const int krow0 = wid * 2 + (lane >> 5);
  const int kgsrc = (lane & 31) ^ (krow0 & 7);
  const unsigned short* kg0 = kbase + (size_t)krow0 * HD + kgsrc * 8;
  const int vd0 = wid * 16 + (lane >> 2);
  const int vgsrc = (lane & 3) ^ ((lane >> 3) & 3);
  const unsigned short* vg0 = vbase + (size_t)vd0 * S_LEN + vgsrc * 8;

#define STAGE_K(buf, ktv)                                                      \
  do {                                                                         \
    _Pragma("unroll")                                                          \
    for (int r = 0; r < 4; r++)                                                \
      gload16(kg0 + (size_t)(ktv) * HD + r * (8 * HD),                         \
              &Kb[buf][wid * 512 + r * 2048]);                                 \
  } while (0)
#define STAGE_V(buf, ktv)                                                      \
  do {                                                                         \
    _Pragma("unroll")                                                          \
    for (int r = 0; r < 4; r++)                                                \
      gload16(vg0 + (ktv) + (size_t)r * (64 * S_LEN),                          \
              &Vb[buf][wid * 512 + r * 2048]);                                 \
  } while (0)

  for (;;){
    if (tid == 0) s_idx = atomicAdd(&ctr[c], 1);
    __syncthreads();
    const int idx = s_idx;
    __syncthreads();
    if (idx >= 32) break;
    const int qt = 31 - idx;                     // heavy-first, item = 64 q-rows

    const int q0 = qt * 64 + (wid & 1) * 32;     // this wave: rows q0..q0+31
    const int qr0 = q0 + lq;                     // row-set 0
    const int qr1 = q0 + 16 + lq;                // row-set 1

    const unsigned short* qbase = qB + ((size_t)(b * NH + h) * S_LEN + qr0) * HD + lk * 8;
    bf16x8 aq0[8], aq1[8];
#pragma unroll
    for (int ks = 0; ks < 8; ks++){
      aq0[ks] = ld_bf8(qbase + ks * 32);
      aq1[ks] = ld_bf8(qbase + 16 * HD + ks * 32);
    }
    asm volatile("s_waitcnt vmcnt(0)" ::: "memory");

    float mi0 = -__builtin_inff(), li0 = 0.f;
    float mi1 = -__builtin_inff(), li1 = 0.f;
    f32x4 oacc0[16] = {};
    f32x4 oacc1[16] = {};

    const int ktmax = qt * 64 + 32;              // last 32-key tile start

    STAGE_K(0, 0);  STAGE_V(0, 0);
    STAGE_K(1, 32); STAGE_V(1, 32);              // ktmax >= 32 always

    int cur = 0;
    for (int kt = 0; kt <= ktmax; kt += 32, cur ^= 1){
      if (kt < ktmax) asm volatile("s_waitcnt vmcnt(8)" ::: "memory");
      else            asm volatile("s_waitcnt vmcnt(0)" ::: "memory");
      __syncthreads();                                   // (A) cur K+V published

      // ---- swapped QK^T: K fragment read ONCE, feeds both row-sets ----
      f32x4 sA0 = {0.f,0.f,0.f,0.f}, sA1 = {0.f,0.f,0.f,0.f};   // set0: keys lo/hi
      f32x4 sC0 = {0.f,0.f,0.f,0.f}, sC1 = {0.f,0.f,0.f,0.f};   // set1: keys lo/hi
#pragma unroll
      for (int ks = 0; ks < 8; ks++){
        const int slot = (((ks * 4 + lk) ^ (lq & 7)) << 3);
        bf16x8 kf0 = ld_bf8(&Kb[cur][lq * 256 + slot]);
        bf16x8 kf1 = ld_bf8(&Kb[cur][(16 + lq) * 256 + slot]);
        sA0 = mfma16(kf0, aq0[ks], sA0);
        sA1 = mfma16(kf1, aq0[ks], sA1);
        sC0 = mfma16(kf0, aq1[ks], sC0);
        sC1 = mfma16(kf1, aq1[ks], sC1);
      }

      // ---- fused online softmax, two row-sets ----
      const unsigned mask32 = bm_lds[kt >> 5];
      const int koff = lk * 4;
      float vA0[4], vA1[4], vC0[4], vC1[4];
#pragma unroll
      for (int j2 = 0; j2 < 4; j2++){
        const bool m0 = ((mask32 >> (koff + j2)) & 1u);
        const bool m1 = ((mask32 >> (16 + koff + j2)) & 1u);
        const int k0 = kt + koff + j2, k1 = kt + 16 + koff + j2;
        vA0[j2] = (k0 <= qr0 && m0) ? sA0[j2] * SCALE_ATT : -__builtin_inff();
        vA1[j2] = (k1 <= qr0 && m1) ? sA1[j2] * SCALE_ATT : -__builtin_inff();
        vC0[j2] = (k0 <= qr1 && m0) ? sC0[j2] * SCALE_ATT : -__builtin_inff();
        vC1[j2] = (k1 <= qr1 && m1) ? sC1[j2] * SCALE_ATT : -__builtin_inff();
      }
      float tm0 = fmaxf(fmaxf(fmaxf(vA0[0], vA0[1]), fmaxf(vA0[2], vA0[3])),
                        fmaxf(fmaxf(vA1[0], vA1[1]), fmaxf(vA1[2], vA1[3])));
      float tm1 = fmaxf(fmaxf(fmaxf(vC0[0], vC0[1]), fmaxf(vC0[2], vC0[3])),
                        fmaxf(fmaxf(vC1[0], vC1[1]), fmaxf(vC1[2], vC1[3])));
      tm0 = fmaxf(tm0, __shfl_xor(tm0, 16, 64));
      tm0 = fmaxf(tm0, __shfl_xor(tm0, 32, 64));
      tm1 = fmaxf(tm1, __shfl_xor(tm1, 16, 64));
      tm1 = fmaxf(tm1, __shfl_xor(tm1, 32, 64));

      float pA0[4], pA1[4], pC0[4], pC1[4];
      if (__all(tm0 <= mi0 + 8.0f && tm1 <= mi1 + 8.0f)){
        const float mns0 = fmaxf(mi0, -1e30f);
        const float mns1 = fmaxf(mi1, -1e30f);
#pragma unroll
        for (int j2 = 0; j2 < 4; j2++){
          pA0[j2] = __expf(vA0[j2] - mns0); pA1[j2] = __expf(vA1[j2] - mns0);
          pC0[j2] = __expf(vC0[j2] - mns1); pC1[j2] = __expf(vC1[j2] - mns1);
        }
        float rs0 = (pA0[0]+pA0[1])+(pA0[2]+pA0[3])+(pA1[0]+pA1[1])+(pA1[2]+pA1[3]);
        float rs1 = (pC0[0]+pC0[1])+(pC0[2]+pC0[3])+(pC1[0]+pC1[1])+(pC1[2]+pC1[3]);
        rs0 += __shfl_xor(rs0, 16, 64);
        rs0 += __shfl_xor(rs0, 32, 64);
        rs1 += __shfl_xor(rs1, 16, 64);
        rs1 += __shfl_xor(rs1, 32, 64);
        li0 += rs0;
        li1 += rs1;
      } else {
        const float mn0  = fmaxf(mi0, tm0);
        const float mn1  = fmaxf(mi1, tm1);
        const float mns0 = fmaxf(mn0, -1e30f);
        const float mns1 = fmaxf(mn1, -1e30f);
#pragma unroll
        for (int j2 = 0; j2 < 4; j2++){
          pA0[j2] = __expf(vA0[j2] - mns0); pA1[j2] = __expf(vA1[j2] - mns0);
          pC0[j2] = __expf(vC0[j2] - mns1); pC1[j2] = __expf(vC1[j2] - mns1);
        }
        const float a0_ = __expf(mi0 - mns0);
        const float a1_ = __expf(mi1 - mns1);
        float rs0 = (pA0[0]+pA0[1])+(pA0[2]+pA0[3])+(pA1[0]+pA1[1])+(pA1[2]+pA1[3]);
        float rs1 = (pC0[0]+pC0[1])+(pC0[2]+pC0[3])+(pC1[0]+pC1[1])+(pC1[2]+pC1[3]);
        rs0 += __shfl_xor(rs0, 16, 64);
        rs0 += __shfl_xor(rs0, 32, 64);
        rs1 += __shfl_xor(rs1, 16, 64);
        rs1 += __shfl_xor(rs1, 32, 64);
        li0 = li0 * a0_ + rs0;
        li1 = li1 * a1_ + rs1;
        mi0 = mn0;
        mi1 = mn1;
        float av0[4], av1[4];
#pragma unroll
        for (int i = 0; i < 4; i++){
          av0[i] = __shfl(a0_, (lane & 48) | (lk * 4 + i), 64);
          av1[i] = __shfl(a1_, (lane & 48) | (lk * 4 + i), 64);
        }
#pragma unroll
        for (int db = 0; db < 16; db++){
          f32x4 o0 = oacc0[db], o1 = oacc1[db];
#pragma unroll
          for (int i = 0; i < 4; i++){ o0[i] *= av0[i]; o1[i] *= av1[i]; }
          oacc0[db] = o0; oacc1[db] = o1;
        }
      }

      // ---- redistribute P -> PV A-fragments (per row-set) ----
      const int sA_ = (((lk & 1) * 2) << 4) | lq;
      const int sB_ = sA_ + 16;
      const bool hi = (lk >= 2);
      I4B8 pau0, pau1;
      {
        const int w0 = cvtpk(pA0[0], pA0[1]), w1 = cvtpk(pA0[2], pA0[3]);
        const int w2 = cvtpk(pA1[0], pA1[1]), w3 = cvtpk(pA1[2], pA1[3]);
        const int a0 = __shfl(w0, sA_, 64), a1 = __shfl(w1, sA_, 64);
        const int b0 = __shfl(w0, sB_, 64), b1 = __shfl(w1, sB_, 64);
        const int c0w = __shfl(w2, sA_, 64), c1w = __shfl(w3, sA_, 64);
        const int d0w = __shfl(w2, sB_, 64), d1w = __shfl(w3, sB_, 64);
        pau0.i.x = hi ? c0w : a0;
        pau0.i.y = hi ? c1w : a1;
        pau0.i.z = hi ? d0w : b0;
        pau0.i.w = hi ? d1w : b1;
      }
      {
        const int w0 = cvtpk(pC0[0], pC0[1]), w1 = cvtpk(pC0[2], pC0[3]);
        const int w2 = cvtpk(pC1[0], pC1[1]), w3 = cvtpk(pC1[2], pC1[3]);
        const int a0 = __shfl(w0, sA_, 64), a1 = __shfl(w1, sA_, 64);
        const int b0 = __shfl(w0, sB_, 64), b1 = __shfl(w1, sB_, 64);
        const int c0w = __shfl(w2, sA_, 64), c1w = __shfl(w3, sA_, 64);
        const int d0w = __shfl(w2, sB_, 64), d1w = __shfl(w3, sB_, 64);
        pau1.i.x = hi ? c0w : a0;
        pau1.i.y = hi ? c1w : a1;
        pau1.i.z = hi ? d0w : b0;
        pau1.i.w = hi ? d1w : b1;
      }

      // ---- PV: V fragment read ONCE, feeds both row-sets ----
      const int vslot = (lk ^ ((lq >> 1) & 3)) << 3;
#pragma unroll
      for (int db = 0; db < 16; db++){
        bf16x8 vf = ld_bf8(&Vb[cur][(db * 16 + lq) * 32 + vslot]);
        oacc0[db] = mfma16(pau0.b, vf, oacc0[db]);
        oacc1[db] = mfma16(pau1.b, vf, oacc1[db]);
      }

      __syncthreads();                                   // (B) all waves done with cur
      if (kt + 64 <= ktmax){ STAGE_K(cur, kt + 64); STAGE_V(cur, kt + 64); }
    }

    // ---- epilogue: both row-sets ----
#pragma unroll
    for (int i = 0; i < 4; i++){
      const float lf0 = __shfl(li0, (lane & 48) | (lk * 4 + i), 64);
      const float lf1 = __shfl(li1, (lane & 48) | (lk * 4 + i), 64);
      const float inv0 = 1.0f / lf0;
      const float inv1 = 1.0f / lf1;
      unsigned short* orow0 = attnO + (size_t)(b * S_LEN + q0      + lk*4 + i) * QSZ + h * HD + lq;
      unsigned short* orow1 = attnO + (size_t)(b * S_LEN + q0 + 16 + lk*4 + i) * QSZ + h * HD + lq;
#pragma unroll
      for (int db = 0; db < 16; db++){
        orow0[db * 16] = f2bf(oacc0[db][i] * inv0);
        orow1[db * 16] = f2bf(oacc1[db][i] * inv1);
      }
    }
  }
#undef STAGE_K
#undef STAGE_V
}

extern "C" void kernel_launch(void* const* d_in, const int* in_sizes, int n_in,
                              void* d_out, int out_size, void* d_ws, size_t ws_size,
                              hipStream_t stream)
{
  const int*   positions = (const int*)  d_in[0];
  const float* hidden    = (const float*)d_in[1];
  const int*   amask     = (const int*)  d_in[2];
  const float* Wqkv      = (const float*)d_in[3];
  const float* Wo        = (const float*)d_in[4];
  const float* qw        = (const float*)d_in[5];
  const float* kw        = (const float*)d_in[6];
  float* out = (float*)d_out;

  char* ws = (char*)d_ws;
  unsigned short* hB    = (unsigned short*)(ws);               // 4096x2560 bf16
  unsigned short* attnO = (unsigned short*)(ws);               // alias (4096x2048 bf16)
  unsigned short* WqT   = (unsigned short*)(ws + 20971520);    // [4096][2560] bf16
  unsigned short* WoT   = (unsigned short*)(ws + 41943040);    // [2560][2048] bf16
  float*          ct    = (float*)        (ws + 52428800);    // [B][128][2048] cos
  float*          st    = (float*)        (ws + 56623104);    // [B][128][2048] sin
  unsigned short* qb    = (unsigned short*)(ws + 119537664);   // [B][NH][S][HD]
  unsigned short* kb    = (unsigned short*)(ws + 136314880);   // [B][NKV][S][HD]
  unsigned short* vt    = (unsigned short*)(ws + 144703488);   // [B][NKV][HD][S]
  unsigned*       bm    = (unsigned*)     (ws + 153092096);   // [B][64] mask bits
  int*            ctr   = (int*)          (ws + 153092608);   // [8] work-queue counters

  cast_bf16_kernel<<<dim3(MROWS * HIDDEN / 1024), 256, 0, stream>>>(hidden, hB, MROWS * HIDDEN);
  tcast_kernel<<<dim3(NQKV / 32, HIDDEN / 32), 256, 0, stream>>>(Wqkv, WqT, HIDDEN, NQKV);
  tcast_kernel<<<dim3(HIDDEN / 32, QSZ / 32), 256, 0, stream>>>(Wo, WoT, QSZ, HIDDEN);
  maskbits_kernel<<<dim3(1), 128, 0, stream>>>(amask, bm, ctr);
  ropetab_kernel<<<dim3(128, BATCH), 256, 0, stream>>>(positions, ct, st);

  // GEMM1 fused: [4096 x 2560] x [2560 x 4096] -> qb/kb/vt (norm+rope in epilogue)
  gemm_qkv_kernel<<<dim3((MROWS/256) * (NQKV/256)), 512, 0, stream>>>(
      hB, WqT, qw, kw, ct, st, qb, kb, vt);

  attn_kernel<<<dim3(256), 256, 0, stream>>>(qb, kb, vt, bm, attnO, ctr);

  // GEMM2: [4096 x 2048] * [2048 x 2560] -> out (f32); grid 160 blocks
  gemm256_kernel<<<dim3((MROWS/256) * (HIDDEN/256)), 512, 0, stream>>>(
      attnO, WoT, out, HIDDEN, QSZ, HIDDEN/256);
}